// Round 1
// baseline (1330.202 us; speedup 1.0000x reference)
//
#include <hip/hip_runtime.h>
#include <hip/hip_bf16.h>

// Problem constants (from reference)
#define N_NODES 50000
#define N_REL   8
#define DIM     128      // IN_DIM == HID == 128
#define N_EDGES 800000
#define N_TRIP  100000

// ---------------------------------------------------------------------------
// counts: cnt[dst*8+rel] += 1   (layer-invariant)
__global__ void count_kernel(const int* __restrict__ edge_index,
                             const int* __restrict__ edge_type,
                             int* __restrict__ cnt) {
    int e = blockIdx.x * blockDim.x + threadIdx.x;
    if (e >= N_EDGES) return;
    int dst = edge_index[N_EDGES + e];
    int r = edge_type[e];
    atomicAdd(&cnt[dst * N_REL + r], 1);
}

// ---------------------------------------------------------------------------
// scatter: mean[seg*128+d] += h[src,d] * 1/max(cnt[seg],1)
// one wave (64 lanes) per edge; lane handles d and d+64
__global__ void scatter_kernel(const float* __restrict__ h,
                               const int* __restrict__ edge_index,
                               const int* __restrict__ edge_type,
                               const int* __restrict__ cnt,
                               float* __restrict__ mean) {
    int e = blockIdx.x * 4 + (threadIdx.x >> 6);
    if (e >= N_EDGES) return;
    int lane = threadIdx.x & 63;
    int src = edge_index[e];
    int dst = edge_index[N_EDGES + e];
    int r = edge_type[e];
    int seg = dst * N_REL + r;
    int c = cnt[seg];
    float inv = 1.0f / (float)(c > 0 ? c : 1);
    const float* hp = h + (size_t)src * DIM;
    float* mp = mean + (size_t)seg * DIM;
    float v0 = hp[lane] * inv;
    float v1 = hp[lane + 64] * inv;
    unsafeAtomicAdd(&mp[lane], v0);
    unsafeAtomicAdd(&mp[lane + 64], v1);
}

// ---------------------------------------------------------------------------
// transform: hout[n,:] = relu(bias + hin[n,:]@root + mean_flat[n,:]@W_flat)
// GEMM: C(N x 128) = A(N x 1152) * B(1152 x 128), A = [hin | mean]
// BM=64, BN=128, BK=16; 256 threads; each thread 4x8 register tile.
__global__ void transform_kernel(const float* __restrict__ hin,   // N x 128
                                 const float* __restrict__ mean,  // N x 1024
                                 const float* __restrict__ root,  // 128 x 128
                                 const float* __restrict__ W,     // 1024 x 128
                                 const float* __restrict__ bias,  // 128
                                 float* __restrict__ hout) {
    __shared__ float As[16][64];    // [k][m]
    __shared__ float Bs[16][128];   // [k][n]
    int tid = threadIdx.x;
    int ty = tid >> 4;              // 0..15
    int tx = tid & 15;              // 0..15
    int row0 = blockIdx.x * 64;

    float acc[4][8];
    #pragma unroll
    for (int i = 0; i < 4; ++i)
        #pragma unroll
        for (int j = 0; j < 8; ++j) acc[i][j] = 0.f;

    #pragma unroll
    for (int piece = 0; piece < 2; ++piece) {
        const float* Ap = piece ? mean : hin;
        const float* Bp = piece ? W : root;
        const int Ks = piece ? 1024 : 128;
        const int astride = piece ? 1024 : 128;
        for (int k0 = 0; k0 < Ks; k0 += 16) {
            // A tile load: lane m=tid&63 row, kq=(tid>>6)*4 columns (float4)
            int m = tid & 63;
            int kq = (tid >> 6) << 2;
            int grow = row0 + m;
            float4 av = make_float4(0.f, 0.f, 0.f, 0.f);
            if (grow < N_NODES)
                av = *(const float4*)(Ap + (size_t)grow * astride + k0 + kq);
            As[kq + 0][m] = av.x;
            As[kq + 1][m] = av.y;
            As[kq + 2][m] = av.z;
            As[kq + 3][m] = av.w;
            // B tile load: 16x128 floats, 2 passes of float4 per thread
            #pragma unroll
            for (int p = 0; p < 2; ++p) {
                int kk = (tid >> 5) + p * 8;
                int nn = (tid & 31) << 2;
                *(float4*)&Bs[kk][nn] =
                    *(const float4*)(Bp + (size_t)(k0 + kk) * 128 + nn);
            }
            __syncthreads();
            #pragma unroll
            for (int k = 0; k < 16; ++k) {
                float4 a = *(const float4*)&As[k][ty << 2];
                float4 b0 = *(const float4*)&Bs[k][tx << 3];
                float4 b1 = *(const float4*)&Bs[k][(tx << 3) + 4];
                float avv[4] = {a.x, a.y, a.z, a.w};
                float bvv[8] = {b0.x, b0.y, b0.z, b0.w, b1.x, b1.y, b1.z, b1.w};
                #pragma unroll
                for (int i = 0; i < 4; ++i)
                    #pragma unroll
                    for (int j = 0; j < 8; ++j)
                        acc[i][j] += avv[i] * bvv[j];
            }
            __syncthreads();
        }
    }

    int mbase = row0 + (ty << 2);
    int nbase = tx << 3;
    #pragma unroll
    for (int i = 0; i < 4; ++i) {
        int grow = mbase + i;
        if (grow >= N_NODES) break;
        #pragma unroll
        for (int j = 0; j < 8; ++j) {
            float v = acc[i][j] + bias[nbase + j];
            hout[(size_t)grow * 128 + nbase + j] = fmaxf(v, 0.f);
        }
    }
}

// ---------------------------------------------------------------------------
// score: out[t] = sum_d h[head,d]*rel_emb[rel,d]*h[tail,d]
__global__ void score_kernel(const float* __restrict__ h,
                             const float* __restrict__ rel_emb,
                             const int* __restrict__ head,
                             const int* __restrict__ rel,
                             const int* __restrict__ tail,
                             float* __restrict__ out) {
    int t = blockIdx.x * 4 + (threadIdx.x >> 6);
    if (t >= N_TRIP) return;
    int lane = threadIdx.x & 63;
    const float* hh = h + (size_t)head[t] * DIM;
    const float* ht = h + (size_t)tail[t] * DIM;
    const float* hr = rel_emb + (size_t)rel[t] * DIM;
    float s = hh[lane] * hr[lane] * ht[lane]
            + hh[lane + 64] * hr[lane + 64] * ht[lane + 64];
    #pragma unroll
    for (int off = 32; off; off >>= 1) s += __shfl_xor(s, off, 64);
    if (lane == 0) out[t] = s;
}

// ---------------------------------------------------------------------------
extern "C" void kernel_launch(void* const* d_in, const int* in_sizes, int n_in,
                              void* d_out, int out_size, void* d_ws, size_t ws_size,
                              hipStream_t stream) {
    const float* emb     = (const float*)d_in[0];
    const float* W0      = (const float*)d_in[1];
    const float* root0   = (const float*)d_in[2];
    const float* b0      = (const float*)d_in[3];
    const float* W1      = (const float*)d_in[4];
    const float* root1   = (const float*)d_in[5];
    const float* b1      = (const float*)d_in[6];
    const float* rel_emb = (const float*)d_in[7];
    const int* edge_index = (const int*)d_in[8];
    const int* edge_type  = (const int*)d_in[9];
    const int* head_idx   = (const int*)d_in[10];
    const int* rel_idx    = (const int*)d_in[11];
    const int* tail_idx   = (const int*)d_in[12];
    float* out = (float*)d_out;

    // workspace layout
    char* ws = (char*)d_ws;
    size_t mean_bytes = (size_t)N_NODES * N_REL * DIM * sizeof(float); // 204.8 MB
    size_t h_bytes    = (size_t)N_NODES * DIM * sizeof(float);         // 25.6 MB
    size_t cnt_bytes  = (size_t)N_NODES * N_REL * sizeof(int);         // 1.6 MB
    float* mean = (float*)ws;
    float* h1   = (float*)(ws + mean_bytes);
    float* h2   = (float*)(ws + mean_bytes + h_bytes);
    int*   cnt  = (int*)(ws + mean_bytes + 2 * h_bytes);
    (void)ws_size; (void)in_sizes; (void)n_in; (void)out_size;

    // counts (layer-invariant)
    hipMemsetAsync(cnt, 0, cnt_bytes, stream);
    count_kernel<<<(N_EDGES + 255) / 256, 256, 0, stream>>>(edge_index, edge_type, cnt);

    dim3 blk256(256);
    int scatter_grid = (N_EDGES + 3) / 4;
    int gemm_grid = (N_NODES + 63) / 64;

    // ---- layer 0 ----
    hipMemsetAsync(mean, 0, mean_bytes, stream);
    scatter_kernel<<<scatter_grid, blk256, 0, stream>>>(emb, edge_index, edge_type, cnt, mean);
    transform_kernel<<<gemm_grid, blk256, 0, stream>>>(emb, mean, root0, W0, b0, h1);

    // ---- layer 1 ----
    hipMemsetAsync(mean, 0, mean_bytes, stream);
    scatter_kernel<<<scatter_grid, blk256, 0, stream>>>(h1, edge_index, edge_type, cnt, mean);
    transform_kernel<<<gemm_grid, blk256, 0, stream>>>(h1, mean, root1, W1, b1, h2);

    // ---- score ----
    score_kernel<<<(N_TRIP + 3) / 4, blk256, 0, stream>>>(h2, rel_emb, head_idx, rel_idx,
                                                          tail_idx, out);
}

// Round 2
// 956.400 us; speedup vs baseline: 1.3908x; 1.3908x over previous
//
#include <hip/hip_runtime.h>
#include <hip/hip_bf16.h>

// Problem constants (from reference)
#define N_NODES 50000
#define N_REL   8
#define DIM     128      // IN_DIM == HID == 128
#define N_EDGES 800000
#define N_TRIP  100000
#define NSEG    (N_NODES * N_REL)   // 400000
#define SCAN_CHUNK 1024
#define N_SCAN_BLOCKS ((NSEG + SCAN_CHUNK - 1) / SCAN_CHUNK)  // 391

// ---------------------------------------------------------------------------
// histogram: cnt[dst*8+rel]++
__global__ void hist_kernel(const int* __restrict__ edge_index,
                            const int* __restrict__ edge_type,
                            int* __restrict__ cnt) {
    int e = blockIdx.x * blockDim.x + threadIdx.x;
    if (e >= N_EDGES) return;
    int dst = edge_index[N_EDGES + e];
    int r = edge_type[e];
    atomicAdd(&cnt[dst * N_REL + r], 1);
}

// ---------------------------------------------------------------------------
// scan1: per-block (1024 elems) exclusive scan of cnt -> offsets, block sum out
__global__ void scan1_kernel(const int* __restrict__ cnt,
                             int* __restrict__ offsets,
                             int* __restrict__ blocksums) {
    __shared__ int sh[256];
    int t = threadIdx.x;
    int base = blockIdx.x * SCAN_CHUNK + t * 4;
    int v[4];
    int s = 0;
    #pragma unroll
    for (int j = 0; j < 4; ++j) {
        v[j] = (base + j < NSEG) ? cnt[base + j] : 0;
        s += v[j];
    }
    sh[t] = s;
    __syncthreads();
    // inclusive scan over 256 thread sums
    #pragma unroll
    for (int off = 1; off < 256; off <<= 1) {
        int x = (t >= off) ? sh[t - off] : 0;
        __syncthreads();
        sh[t] += x;
        __syncthreads();
    }
    int ex = sh[t] - s;  // exclusive prefix for this thread
    #pragma unroll
    for (int j = 0; j < 4; ++j) {
        if (base + j < NSEG) offsets[base + j] = ex;
        ex += v[j];
    }
    if (t == 255) blocksums[blockIdx.x] = sh[255];
}

// ---------------------------------------------------------------------------
// scan2: single block, exclusive scan of the 391 block sums (in place)
__global__ void scan2_kernel(int* __restrict__ blocksums) {
    __shared__ int sh[512];
    int t = threadIdx.x;
    int orig = (t < N_SCAN_BLOCKS) ? blocksums[t] : 0;
    sh[t] = orig;
    __syncthreads();
    #pragma unroll
    for (int off = 1; off < 512; off <<= 1) {
        int x = (t >= off) ? sh[t - off] : 0;
        __syncthreads();
        sh[t] += x;
        __syncthreads();
    }
    if (t < N_SCAN_BLOCKS) blocksums[t] = sh[t] - orig;  // exclusive
}

// ---------------------------------------------------------------------------
// scan3: add block offsets; also init cursor copy and the sentinel
__global__ void scan3_kernel(int* __restrict__ offsets,
                             const int* __restrict__ blocksums,
                             int* __restrict__ cursor) {
    int t = threadIdx.x;
    int boff = blocksums[blockIdx.x];
    int base = blockIdx.x * SCAN_CHUNK + t * 4;
    #pragma unroll
    for (int j = 0; j < 4; ++j) {
        int i = base + j;
        if (i < NSEG) {
            int v = offsets[i] + boff;
            offsets[i] = v;
            cursor[i] = v;
        }
    }
    if (blockIdx.x == 0 && t == 0) offsets[NSEG] = N_EDGES;
}

// ---------------------------------------------------------------------------
// reorder: sorted_src[pos] = src, pos = cursor[seg]++
__global__ void reorder_kernel(const int* __restrict__ edge_index,
                               const int* __restrict__ edge_type,
                               int* __restrict__ cursor,
                               int* __restrict__ sorted_src) {
    int e = blockIdx.x * blockDim.x + threadIdx.x;
    if (e >= N_EDGES) return;
    int src = edge_index[e];
    int dst = edge_index[N_EDGES + e];
    int r = edge_type[e];
    int seg = dst * N_REL + r;
    int pos = atomicAdd(&cursor[seg], 1);
    sorted_src[pos] = src;
}

// ---------------------------------------------------------------------------
// aggregate: one wave per segment; mean[seg,:] = sum(h[src,:]) / max(cnt,1)
__global__ void aggregate_kernel(const float* __restrict__ h,
                                 const int* __restrict__ offsets,
                                 const int* __restrict__ sorted_src,
                                 float* __restrict__ mean) {
    int seg = blockIdx.x * 4 + (threadIdx.x >> 6);
    if (seg >= NSEG) return;
    int lane = threadIdx.x & 63;
    int off = offsets[seg];
    int end = offsets[seg + 1];
    float a0 = 0.f, a1 = 0.f;
    for (int i = off; i < end; ++i) {
        int s = sorted_src[i];
        const float* hp = h + (size_t)s * DIM;
        a0 += hp[lane];
        a1 += hp[lane + 64];
    }
    int c = end - off;
    float inv = (c > 0) ? 1.0f / (float)c : 0.f;
    float* mp = mean + (size_t)seg * DIM;
    mp[lane] = a0 * inv;
    mp[lane + 64] = a1 * inv;
}

// ---------------------------------------------------------------------------
// transform: hout[n,:] = relu(bias + hin[n,:]@root + mean_flat[n,:]@W_flat)
// GEMM: C(N x 128) = A(N x 1152) * B(1152 x 128), A = [hin | mean]
// BM=64, BN=128, BK=16; 256 threads; each thread 4x8 register tile.
__global__ void transform_kernel(const float* __restrict__ hin,   // N x 128
                                 const float* __restrict__ mean,  // N x 1024
                                 const float* __restrict__ root,  // 128 x 128
                                 const float* __restrict__ W,     // 1024 x 128
                                 const float* __restrict__ bias,  // 128
                                 float* __restrict__ hout) {
    __shared__ float As[16][64];    // [k][m]
    __shared__ float Bs[16][128];   // [k][n]
    int tid = threadIdx.x;
    int ty = tid >> 4;              // 0..15
    int tx = tid & 15;              // 0..15
    int row0 = blockIdx.x * 64;

    float acc[4][8];
    #pragma unroll
    for (int i = 0; i < 4; ++i)
        #pragma unroll
        for (int j = 0; j < 8; ++j) acc[i][j] = 0.f;

    #pragma unroll
    for (int piece = 0; piece < 2; ++piece) {
        const float* Ap = piece ? mean : hin;
        const float* Bp = piece ? W : root;
        const int Ks = piece ? 1024 : 128;
        const int astride = piece ? 1024 : 128;
        for (int k0 = 0; k0 < Ks; k0 += 16) {
            int m = tid & 63;
            int kq = (tid >> 6) << 2;
            int grow = row0 + m;
            float4 av = make_float4(0.f, 0.f, 0.f, 0.f);
            if (grow < N_NODES)
                av = *(const float4*)(Ap + (size_t)grow * astride + k0 + kq);
            As[kq + 0][m] = av.x;
            As[kq + 1][m] = av.y;
            As[kq + 2][m] = av.z;
            As[kq + 3][m] = av.w;
            #pragma unroll
            for (int p = 0; p < 2; ++p) {
                int kk = (tid >> 5) + p * 8;
                int nn = (tid & 31) << 2;
                *(float4*)&Bs[kk][nn] =
                    *(const float4*)(Bp + (size_t)(k0 + kk) * 128 + nn);
            }
            __syncthreads();
            #pragma unroll
            for (int k = 0; k < 16; ++k) {
                float4 a = *(const float4*)&As[k][ty << 2];
                float4 b0 = *(const float4*)&Bs[k][tx << 3];
                float4 b1 = *(const float4*)&Bs[k][(tx << 3) + 4];
                float avv[4] = {a.x, a.y, a.z, a.w};
                float bvv[8] = {b0.x, b0.y, b0.z, b0.w, b1.x, b1.y, b1.z, b1.w};
                #pragma unroll
                for (int i = 0; i < 4; ++i)
                    #pragma unroll
                    for (int j = 0; j < 8; ++j)
                        acc[i][j] += avv[i] * bvv[j];
            }
            __syncthreads();
        }
    }

    int mbase = row0 + (ty << 2);
    int nbase = tx << 3;
    #pragma unroll
    for (int i = 0; i < 4; ++i) {
        int grow = mbase + i;
        if (grow >= N_NODES) break;
        #pragma unroll
        for (int j = 0; j < 8; ++j) {
            float v = acc[i][j] + bias[nbase + j];
            hout[(size_t)grow * 128 + nbase + j] = fmaxf(v, 0.f);
        }
    }
}

// ---------------------------------------------------------------------------
// score: out[t] = sum_d h[head,d]*rel_emb[rel,d]*h[tail,d]
__global__ void score_kernel(const float* __restrict__ h,
                             const float* __restrict__ rel_emb,
                             const int* __restrict__ head,
                             const int* __restrict__ rel,
                             const int* __restrict__ tail,
                             float* __restrict__ out) {
    int t = blockIdx.x * 4 + (threadIdx.x >> 6);
    if (t >= N_TRIP) return;
    int lane = threadIdx.x & 63;
    const float* hh = h + (size_t)head[t] * DIM;
    const float* ht = h + (size_t)tail[t] * DIM;
    const float* hr = rel_emb + (size_t)rel[t] * DIM;
    float s = hh[lane] * hr[lane] * ht[lane]
            + hh[lane + 64] * hr[lane + 64] * ht[lane + 64];
    #pragma unroll
    for (int off = 32; off; off >>= 1) s += __shfl_xor(s, off, 64);
    if (lane == 0) out[t] = s;
}

// ---------------------------------------------------------------------------
extern "C" void kernel_launch(void* const* d_in, const int* in_sizes, int n_in,
                              void* d_out, int out_size, void* d_ws, size_t ws_size,
                              hipStream_t stream) {
    const float* emb     = (const float*)d_in[0];
    const float* W0      = (const float*)d_in[1];
    const float* root0   = (const float*)d_in[2];
    const float* b0      = (const float*)d_in[3];
    const float* W1      = (const float*)d_in[4];
    const float* root1   = (const float*)d_in[5];
    const float* b1      = (const float*)d_in[6];
    const float* rel_emb = (const float*)d_in[7];
    const int* edge_index = (const int*)d_in[8];
    const int* edge_type  = (const int*)d_in[9];
    const int* head_idx   = (const int*)d_in[10];
    const int* rel_idx    = (const int*)d_in[11];
    const int* tail_idx   = (const int*)d_in[12];
    float* out = (float*)d_out;

    // workspace layout (257.6 MB total, same footprint as round 1):
    //   mean    : [0, 204.8 MB)           -- written by aggregate (covers all segs)
    //     cnt      aliases mean + 0       (dead before aggregate writes mean)
    //     cursor   aliases mean + 2 MB    (dead before aggregate)
    //     blocksums aliases mean + 4 MB   (dead before aggregate)
    //   h1      : [204.8, 230.4 MB)
    //   h2      : [230.4, 256.0 MB)
    //     sorted_src aliases h2           (dead before transform #2 writes h2)
    //   offsets : [256.0 MB, +NSEG+1 ints)
    char* ws = (char*)d_ws;
    size_t mean_bytes = (size_t)NSEG * DIM * sizeof(float);       // 204.8 MB
    size_t h_bytes    = (size_t)N_NODES * DIM * sizeof(float);    // 25.6 MB
    float* mean = (float*)ws;
    int*   cnt       = (int*)ws;
    int*   cursor    = (int*)(ws + (2 << 20));
    int*   blocksums = (int*)(ws + (4 << 20));
    float* h1 = (float*)(ws + mean_bytes);
    float* h2 = (float*)(ws + mean_bytes + h_bytes);
    int*   sorted_src = (int*)h2;
    int*   offsets = (int*)(ws + mean_bytes + 2 * h_bytes);
    (void)ws_size; (void)in_sizes; (void)n_in; (void)out_size;

    dim3 blk256(256);

    // ---- sort edges by (dst, rel) segment (layer-invariant, done once) ----
    hipMemsetAsync(cnt, 0, (size_t)NSEG * sizeof(int), stream);
    hist_kernel<<<(N_EDGES + 255) / 256, blk256, 0, stream>>>(edge_index, edge_type, cnt);
    scan1_kernel<<<N_SCAN_BLOCKS, blk256, 0, stream>>>(cnt, offsets, blocksums);
    scan2_kernel<<<1, 512, 0, stream>>>(blocksums);
    scan3_kernel<<<N_SCAN_BLOCKS, blk256, 0, stream>>>(offsets, blocksums, cursor);
    reorder_kernel<<<(N_EDGES + 255) / 256, blk256, 0, stream>>>(edge_index, edge_type,
                                                                 cursor, sorted_src);

    int agg_grid = (NSEG + 3) / 4;
    int gemm_grid = (N_NODES + 63) / 64;

    // ---- layer 0 ----
    aggregate_kernel<<<agg_grid, blk256, 0, stream>>>(emb, offsets, sorted_src, mean);
    transform_kernel<<<gemm_grid, blk256, 0, stream>>>(emb, mean, root0, W0, b0, h1);

    // ---- layer 1 ----
    aggregate_kernel<<<agg_grid, blk256, 0, stream>>>(h1, offsets, sorted_src, mean);
    transform_kernel<<<gemm_grid, blk256, 0, stream>>>(h1, mean, root1, W1, b1, h2);

    // ---- score ----
    score_kernel<<<(N_TRIP + 3) / 4, blk256, 0, stream>>>(h2, rel_emb, head_idx, rel_idx,
                                                          tail_idx, out);
}

// Round 3
// 518.003 us; speedup vs baseline: 2.5679x; 1.8463x over previous
//
#include <hip/hip_runtime.h>
#include <hip/hip_bf16.h>

// Problem constants (from reference)
#define N_NODES 50000
#define N_REL   8
#define DIM     128      // IN_DIM == HID == 128
#define N_EDGES 800000
#define N_TRIP  100000
#define NSEG    (N_NODES * N_REL)   // 400000
#define SCAN_CHUNK 1024
#define N_SCAN_BLOCKS ((NSEG + SCAN_CHUNK - 1) / SCAN_CHUNK)  // 391

typedef __attribute__((ext_vector_type(8))) short bf16x8;
typedef __attribute__((ext_vector_type(4))) float f32x4;

static __device__ __forceinline__ unsigned short f2b(float f) {
    __hip_bfloat16 h = __float2bfloat16(f);
    return *reinterpret_cast<unsigned short*>(&h);
}
static __device__ __forceinline__ float b2f(unsigned short u) {
    __hip_bfloat16 h;
    *reinterpret_cast<unsigned short*>(&h) = u;
    return __bfloat162float(h);
}

// ---------------------------------------------------------------------------
// histogram: cnt[dst*8+rel]++
__global__ void hist_kernel(const int* __restrict__ edge_index,
                            const int* __restrict__ edge_type,
                            int* __restrict__ cnt) {
    int e = blockIdx.x * blockDim.x + threadIdx.x;
    if (e >= N_EDGES) return;
    int dst = edge_index[N_EDGES + e];
    int r = edge_type[e];
    atomicAdd(&cnt[dst * N_REL + r], 1);
}

// ---------------------------------------------------------------------------
// scan1: per-block (1024 elems) exclusive scan of cnt -> offsets, block sum out
__global__ void scan1_kernel(const int* __restrict__ cnt,
                             int* __restrict__ offsets,
                             int* __restrict__ blocksums) {
    __shared__ int sh[256];
    int t = threadIdx.x;
    int base = blockIdx.x * SCAN_CHUNK + t * 4;
    int v[4];
    int s = 0;
    #pragma unroll
    for (int j = 0; j < 4; ++j) {
        v[j] = (base + j < NSEG) ? cnt[base + j] : 0;
        s += v[j];
    }
    sh[t] = s;
    __syncthreads();
    #pragma unroll
    for (int off = 1; off < 256; off <<= 1) {
        int x = (t >= off) ? sh[t - off] : 0;
        __syncthreads();
        sh[t] += x;
        __syncthreads();
    }
    int ex = sh[t] - s;
    #pragma unroll
    for (int j = 0; j < 4; ++j) {
        if (base + j < NSEG) offsets[base + j] = ex;
        ex += v[j];
    }
    if (t == 255) blocksums[blockIdx.x] = sh[255];
}

// ---------------------------------------------------------------------------
// scan2: single block, exclusive scan of the 391 block sums (in place)
__global__ void scan2_kernel(int* __restrict__ blocksums) {
    __shared__ int sh[512];
    int t = threadIdx.x;
    int orig = (t < N_SCAN_BLOCKS) ? blocksums[t] : 0;
    sh[t] = orig;
    __syncthreads();
    #pragma unroll
    for (int off = 1; off < 512; off <<= 1) {
        int x = (t >= off) ? sh[t - off] : 0;
        __syncthreads();
        sh[t] += x;
        __syncthreads();
    }
    if (t < N_SCAN_BLOCKS) blocksums[t] = sh[t] - orig;
}

// ---------------------------------------------------------------------------
// scan3: add block offsets; also init cursor copy and the sentinel
__global__ void scan3_kernel(int* __restrict__ offsets,
                             const int* __restrict__ blocksums,
                             int* __restrict__ cursor) {
    int t = threadIdx.x;
    int boff = blocksums[blockIdx.x];
    int base = blockIdx.x * SCAN_CHUNK + t * 4;
    #pragma unroll
    for (int j = 0; j < 4; ++j) {
        int i = base + j;
        if (i < NSEG) {
            int v = offsets[i] + boff;
            offsets[i] = v;
            cursor[i] = v;
        }
    }
    if (blockIdx.x == 0 && t == 0) offsets[NSEG] = N_EDGES;
}

// ---------------------------------------------------------------------------
// reorder: sorted_src[pos] = src, pos = cursor[seg]++
__global__ void reorder_kernel(const int* __restrict__ edge_index,
                               const int* __restrict__ edge_type,
                               int* __restrict__ cursor,
                               int* __restrict__ sorted_src) {
    int e = blockIdx.x * blockDim.x + threadIdx.x;
    if (e >= N_EDGES) return;
    int src = edge_index[e];
    int dst = edge_index[N_EDGES + e];
    int r = edge_type[e];
    int seg = dst * N_REL + r;
    int pos = atomicAdd(&cursor[seg], 1);
    sorted_src[pos] = src;
}

// ---------------------------------------------------------------------------
// cvt_emb: fp32 -> bf16, 2 elems/thread (packed)
__global__ void cvt_emb_kernel(const float* __restrict__ src,
                               unsigned short* __restrict__ dst) {
    int i = blockIdx.x * blockDim.x + threadIdx.x;   // pair index
    const int npair = N_NODES * DIM / 2;
    if (i >= npair) return;
    float2 v = ((const float2*)src)[i];
    unsigned int p = (unsigned int)f2b(v.x) | ((unsigned int)f2b(v.y) << 16);
    ((unsigned int*)dst)[i] = p;
}

// ---------------------------------------------------------------------------
// cvt_w: build Wt[n][k] (bf16, n-major, k = 0..1151) from root (128x128) and
// W (8x128x128 = 1024x128), both fp32 row-major [k][n].
__global__ void cvt_w_kernel(const float* __restrict__ root,
                             const float* __restrict__ W,
                             unsigned short* __restrict__ Wt) {
    int n = blockIdx.x;          // 0..127
    for (int k = threadIdx.x; k < 1152; k += blockDim.x) {
        float v = (k < 128) ? root[k * 128 + n] : W[(size_t)(k - 128) * 128 + n];
        Wt[(size_t)n * 1152 + k] = f2b(v);
    }
}

// ---------------------------------------------------------------------------
// aggregate: one wave per segment; meanb[seg,:] = bf16(sum(hb[src,:]) / max(c,1))
// lane handles packed columns 2*lane, 2*lane+1.
__global__ void aggregate_kernel(const unsigned short* __restrict__ hb,
                                 const int* __restrict__ offsets,
                                 const int* __restrict__ sorted_src,
                                 unsigned short* __restrict__ meanb) {
    int seg = blockIdx.x * 4 + (threadIdx.x >> 6);
    if (seg >= NSEG) return;
    int lane = threadIdx.x & 63;
    int off = offsets[seg];
    int end = offsets[seg + 1];
    float a0 = 0.f, a1 = 0.f;
    for (int i = off; i < end; ++i) {
        int s = sorted_src[i];
        unsigned int p = ((const unsigned int*)(hb + (size_t)s * DIM))[lane];
        a0 += b2f((unsigned short)(p & 0xffff));
        a1 += b2f((unsigned short)(p >> 16));
    }
    int c = end - off;
    float inv = (c > 0) ? 1.0f / (float)c : 0.f;
    unsigned int po = (unsigned int)f2b(a0 * inv) |
                      ((unsigned int)f2b(a1 * inv) << 16);
    ((unsigned int*)(meanb + (size_t)seg * DIM))[lane] = po;
}

// ---------------------------------------------------------------------------
// transform (MFMA bf16): hout = bf16(relu(bias + [hb | meanb] @ [root;W]))
// C(50000 x 128) = A(50000 x 1152) x B(1152 x 128), all bf16, fp32 acc.
// BM=64, BN=128, BK=64. 256 threads = 4 waves; wave (wm,wn) computes a
// 32x64 quadrant as 2x4 tiles of mfma_f32_16x16x32_bf16.
__global__ __launch_bounds__(256) void transform_mfma(
        const unsigned short* __restrict__ hb,     // N x 128
        const unsigned short* __restrict__ meanb,  // N x 1024
        const unsigned short* __restrict__ Wt,     // 128 x 1152 (n-major)
        const float* __restrict__ bias,            // 128
        unsigned short* __restrict__ hout) {       // N x 128
    __shared__ unsigned short As[64][72];    // [m][k], +8 pad
    __shared__ unsigned short Bs[128][72];   // [n][k], +8 pad
    int tid = threadIdx.x;
    int wave = tid >> 6, lane = tid & 63;
    int wm = wave & 1, wn = wave >> 1;
    int quad = lane >> 4, l16 = lane & 15;
    int row0 = blockIdx.x * 64;

    f32x4 acc[2][4];
    #pragma unroll
    for (int i = 0; i < 2; ++i)
        #pragma unroll
        for (int j = 0; j < 4; ++j) acc[i][j] = (f32x4){0.f, 0.f, 0.f, 0.f};

    for (int s = 0; s < 18; ++s) {
        // ---- stage A tile (64 x 64 bf16) ----
        const unsigned short* Ap;
        int astride, aoff;
        if (s < 2) { Ap = hb;    astride = 128;  aoff = s * 64; }
        else       { Ap = meanb; astride = 1024; aoff = (s - 2) * 64; }
        {
            int r = tid >> 2, c0 = (tid & 3) * 16;
            int grow = row0 + r;
            if (grow >= N_NODES) grow = N_NODES - 1;   // clamp (rows unused)
            const unsigned short* gp = Ap + (size_t)grow * astride + aoff + c0;
            *(bf16x8*)&As[r][c0]     = *(const bf16x8*)(gp);
            *(bf16x8*)&As[r][c0 + 8] = *(const bf16x8*)(gp + 8);
        }
        // ---- stage B tile (128 x 64 bf16) from Wt ----
        {
            int r = tid >> 1, c0 = (tid & 1) * 32;
            const unsigned short* gp = Wt + (size_t)r * 1152 + s * 64 + c0;
            *(bf16x8*)&Bs[r][c0]      = *(const bf16x8*)(gp);
            *(bf16x8*)&Bs[r][c0 + 8]  = *(const bf16x8*)(gp + 8);
            *(bf16x8*)&Bs[r][c0 + 16] = *(const bf16x8*)(gp + 16);
            *(bf16x8*)&Bs[r][c0 + 24] = *(const bf16x8*)(gp + 24);
        }
        __syncthreads();
        #pragma unroll
        for (int kk = 0; kk < 2; ++kk) {
            bf16x8 afr[2], bfr[4];
            #pragma unroll
            for (int i = 0; i < 2; ++i)
                afr[i] = *(const bf16x8*)&As[wm * 32 + i * 16 + l16][kk * 32 + quad * 8];
            #pragma unroll
            for (int j = 0; j < 4; ++j)
                bfr[j] = *(const bf16x8*)&Bs[wn * 64 + j * 16 + l16][kk * 32 + quad * 8];
            #pragma unroll
            for (int i = 0; i < 2; ++i)
                #pragma unroll
                for (int j = 0; j < 4; ++j)
                    acc[i][j] = __builtin_amdgcn_mfma_f32_16x16x32_bf16(
                        afr[i], bfr[j], acc[i][j], 0, 0, 0);
        }
        __syncthreads();
    }

    // epilogue: C/D layout col=lane&15, row=(lane>>4)*4+reg
    #pragma unroll
    for (int i = 0; i < 2; ++i) {
        int gr0 = row0 + wm * 32 + i * 16 + quad * 4;
        #pragma unroll
        for (int j = 0; j < 4; ++j) {
            int gc = wn * 64 + j * 16 + l16;
            float bv = bias[gc];
            #pragma unroll
            for (int r = 0; r < 4; ++r) {
                int grow = gr0 + r;
                if (grow < N_NODES) {
                    float v = acc[i][j][r] + bv;
                    hout[(size_t)grow * 128 + gc] = f2b(fmaxf(v, 0.f));
                }
            }
        }
    }
}

// ---------------------------------------------------------------------------
// score: out[t] = sum_d h[head,d]*rel_emb[rel,d]*h[tail,d]  (h in bf16)
__global__ void score_kernel(const unsigned short* __restrict__ hb,
                             const float* __restrict__ rel_emb,
                             const int* __restrict__ head,
                             const int* __restrict__ rel,
                             const int* __restrict__ tail,
                             float* __restrict__ out) {
    int t = blockIdx.x * 4 + (threadIdx.x >> 6);
    if (t >= N_TRIP) return;
    int lane = threadIdx.x & 63;
    unsigned int ph = ((const unsigned int*)(hb + (size_t)head[t] * DIM))[lane];
    unsigned int pt = ((const unsigned int*)(hb + (size_t)tail[t] * DIM))[lane];
    float2 rr = ((const float2*)(rel_emb + (size_t)rel[t] * DIM))[lane];
    float s = b2f((unsigned short)(ph & 0xffff)) * rr.x * b2f((unsigned short)(pt & 0xffff))
            + b2f((unsigned short)(ph >> 16))   * rr.y * b2f((unsigned short)(pt >> 16));
    #pragma unroll
    for (int off = 32; off; off >>= 1) s += __shfl_xor(s, off, 64);
    if (lane == 0) out[t] = s;
}

// ---------------------------------------------------------------------------
extern "C" void kernel_launch(void* const* d_in, const int* in_sizes, int n_in,
                              void* d_out, int out_size, void* d_ws, size_t ws_size,
                              hipStream_t stream) {
    const float* emb     = (const float*)d_in[0];
    const float* W0      = (const float*)d_in[1];
    const float* root0   = (const float*)d_in[2];
    const float* b0      = (const float*)d_in[3];
    const float* W1      = (const float*)d_in[4];
    const float* root1   = (const float*)d_in[5];
    const float* b1      = (const float*)d_in[6];
    const float* rel_emb = (const float*)d_in[7];
    const int* edge_index = (const int*)d_in[8];
    const int* edge_type  = (const int*)d_in[9];
    const int* head_idx   = (const int*)d_in[10];
    const int* rel_idx    = (const int*)d_in[11];
    const int* tail_idx   = (const int*)d_in[12];
    float* out = (float*)d_out;

    // workspace layout (~146 MB):
    //   meanb   : [0, 102.4 MB)  bf16 N x 1024
    //     cnt / cursor / blocksums alias meanb head (dead before aggregate)
    //   embb    : bf16 N x 128   (12.8 MB)
    //   h1b     : bf16 N x 128
    //   h2b     : bf16 N x 128
    //   Wt0,Wt1 : bf16 128 x 1152 each
    //   offsets : (NSEG+1) ints
    //   sorted_src : N_EDGES ints
    char* ws = (char*)d_ws;
    size_t meanb_bytes = (size_t)NSEG * DIM * sizeof(unsigned short);  // 102.4 MB
    size_t hb_bytes    = (size_t)N_NODES * DIM * sizeof(unsigned short);
    size_t wt_bytes    = (size_t)128 * 1152 * sizeof(unsigned short);
    unsigned short* meanb = (unsigned short*)ws;
    int* cnt       = (int*)ws;
    int* cursor    = (int*)(ws + (2 << 20));
    int* blocksums = (int*)(ws + (4 << 20));
    char* p = ws + meanb_bytes;
    unsigned short* embb = (unsigned short*)p; p += hb_bytes;
    unsigned short* h1b  = (unsigned short*)p; p += hb_bytes;
    unsigned short* h2b  = (unsigned short*)p; p += hb_bytes;
    unsigned short* Wt0  = (unsigned short*)p; p += wt_bytes;
    unsigned short* Wt1  = (unsigned short*)p; p += wt_bytes;
    int* offsets    = (int*)p; p += (size_t)(NSEG + 1) * sizeof(int);
    int* sorted_src = (int*)p;
    (void)ws_size; (void)in_sizes; (void)n_in; (void)out_size;

    dim3 blk256(256);

    // ---- sort edges by (dst, rel) segment (layer-invariant, done once) ----
    hipMemsetAsync(cnt, 0, (size_t)NSEG * sizeof(int), stream);
    hist_kernel<<<(N_EDGES + 255) / 256, blk256, 0, stream>>>(edge_index, edge_type, cnt);
    scan1_kernel<<<N_SCAN_BLOCKS, blk256, 0, stream>>>(cnt, offsets, blocksums);
    scan2_kernel<<<1, 512, 0, stream>>>(blocksums);
    scan3_kernel<<<N_SCAN_BLOCKS, blk256, 0, stream>>>(offsets, blocksums, cursor);
    reorder_kernel<<<(N_EDGES + 255) / 256, blk256, 0, stream>>>(edge_index, edge_type,
                                                                 cursor, sorted_src);

    // ---- precision conversions (emb, weights) ----
    cvt_emb_kernel<<<(N_NODES * DIM / 2 + 255) / 256, blk256, 0, stream>>>(emb, embb);
    cvt_w_kernel<<<128, blk256, 0, stream>>>(root0, W0, Wt0);
    cvt_w_kernel<<<128, blk256, 0, stream>>>(root1, W1, Wt1);

    int agg_grid = NSEG / 4;                       // 100000
    int gemm_grid = (N_NODES + 63) / 64;           // 782

    // ---- layer 0 ----
    aggregate_kernel<<<agg_grid, blk256, 0, stream>>>(embb, offsets, sorted_src, meanb);
    transform_mfma<<<gemm_grid, blk256, 0, stream>>>(embb, meanb, Wt0, b0, h1b);

    // ---- layer 1 ----
    aggregate_kernel<<<agg_grid, blk256, 0, stream>>>(h1b, offsets, sorted_src, meanb);
    transform_mfma<<<gemm_grid, blk256, 0, stream>>>(h1b, meanb, Wt1, b1, h2b);

    // ---- score ----
    score_kernel<<<(N_TRIP + 3) / 4, blk256, 0, stream>>>(h2b, rel_emb, head_idx, rel_idx,
                                                          tail_idx, out);
}